// Round 6
// baseline (231.543 us; speedup 1.0000x reference)
//
#include <hip/hip_runtime.h>
#include <math.h>

// ----------------------------------------------------------------------------
// SingleHeadSelfAttention, N=8192, DIM=128, fp32 in/out.
// R6: attn restructured: NO K/V LDS staging, NO __syncthreads. K- and V-
//     fragments are loaded directly from global (b128, 64B segments) — the
//     K/V working set per XCD is 512KB and chunk==blockIdx&7 matches the
//     XCD round-robin, so these are L2 hits. LDS holds only the wave-private
//     P round-trip (C->A layout), 8KB/WG. Waves free-run (no barrier drain).
// No running max (scores bounded: exp2-arg <= ~8.4, fp32 can't overflow);
// row-sum l via ones-column MFMA; Q pre-scaled by scale*log2e.
// ----------------------------------------------------------------------------

typedef __bf16 bf16x8 __attribute__((ext_vector_type(8)));
typedef float f32x4 __attribute__((ext_vector_type(4)));
typedef unsigned int u32x4 __attribute__((ext_vector_type(4)));
typedef unsigned int u32x2 __attribute__((ext_vector_type(2)));
typedef unsigned short us16;

#define NTOK 8192
#define CHUNKS 8

// scale * log2(e);  scale = 1/sqrt(128)
static constexpr float SCALE_L2E = 0.08838834764831845f * 1.4426950408889634f;

__device__ __forceinline__ unsigned f2bf_u(float x) {
    unsigned u = __builtin_bit_cast(unsigned, x);
    return (u + 0x7FFFu + ((u >> 16) & 1u)) >> 16;   // RNE, no NaN inputs here
}

// pack two fp32 -> bf16x2 (round-half-up; bias cancels because l uses same P)
__device__ __forceinline__ unsigned pk_bf16(float x, float y) {
    unsigned a = __builtin_bit_cast(unsigned, x) + 0x8000u;
    unsigned b = __builtin_bit_cast(unsigned, y) + 0x8000u;
#if __has_builtin(__builtin_amdgcn_perm)
    return __builtin_amdgcn_perm(b, a, 0x07060302u);  // {b.hi16 : a.hi16}
#else
    return (a >> 16) | (b & 0xFFFF0000u);
#endif
}

__device__ __forceinline__ bf16x8 ld_frag(const us16* p) {
    u32x4 u = *reinterpret_cast<const u32x4*>(p);
    return __builtin_bit_cast(bf16x8, u);
}

// load 8 consecutive fp32, convert RNE -> bf16x8 fragment
__device__ __forceinline__ bf16x8 cvt_frag(const float* p) {
    f32x4 a = *reinterpret_cast<const f32x4*>(p);
    f32x4 b = *reinterpret_cast<const f32x4*>(p + 4);
    u32x4 o;
    o[0] = f2bf_u(a[0]) | (f2bf_u(a[1]) << 16);
    o[1] = f2bf_u(a[2]) | (f2bf_u(a[3]) << 16);
    o[2] = f2bf_u(b[0]) | (f2bf_u(b[1]) << 16);
    o[3] = f2bf_u(b[2]) | (f2bf_u(b[3]) << 16);
    return __builtin_bit_cast(bf16x8, o);
}

// ------------------------------------------------------------- QKV projection
// Reads fp32 x and fp32 W directly (in-register bf16 cast).
// z=0 -> Q bf16 row-major, PRE-SCALED by scale*log2e; z=1 -> K row-major;
// z=2 -> V^T bf16 [128 x 8192]
__global__ __launch_bounds__(256) void proj_qkv(
    const float* __restrict__ x,
    const float* __restrict__ wq, const float* __restrict__ bq,
    const float* __restrict__ wk, const float* __restrict__ bk,
    const float* __restrict__ wv, const float* __restrict__ bv,
    us16* __restrict__ Qb, us16* __restrict__ Kb, us16* __restrict__ Vt)
{
    int z = blockIdx.x >> 7;
    int tile = blockIdx.x & 127;
    const float* W = z == 0 ? wq : z == 1 ? wk : wv;
    const float* bias = z == 0 ? bq : z == 1 ? bk : bv;
    float osc = z == 0 ? SCALE_L2E : 1.0f;

    int w = threadIdx.x >> 6, lane = threadIdx.x & 63;
    int quad = lane >> 4, l15 = lane & 15;
    int rbase = tile * 64 + w * 16;

    bf16x8 af[4];
#pragma unroll
    for (int ks = 0; ks < 4; ++ks)
        af[ks] = cvt_frag(x + (size_t)(rbase + l15) * 128 + ks * 32 + quad * 8);

    f32x4 acc[8];
#pragma unroll
    for (int nt = 0; nt < 8; ++nt) acc[nt] = f32x4{0.f, 0.f, 0.f, 0.f};

#pragma unroll
    for (int nt = 0; nt < 8; ++nt) {
#pragma unroll
        for (int ks = 0; ks < 4; ++ks) {
            bf16x8 bf = cvt_frag(W + (nt * 16 + l15) * 128 + ks * 32 + quad * 8);
            acc[nt] = __builtin_amdgcn_mfma_f32_16x16x32_bf16(af[ks], bf, acc[nt], 0, 0, 0);
        }
    }

#pragma unroll
    for (int nt = 0; nt < 8; ++nt) {
        float bb = bias[nt * 16 + l15];
        if (z < 2) {
            us16* Out = z == 0 ? Qb : Kb;
#pragma unroll
            for (int r = 0; r < 4; ++r)
                Out[(rbase + quad * 4 + r) * 128 + nt * 16 + l15] =
                    (us16)f2bf_u((acc[nt][r] + bb) * osc);
        } else {
            int d = nt * 16 + l15, r0 = rbase + quad * 4;
            u32x2 pk;
            pk[0] = f2bf_u(acc[nt][0] + bb) | (f2bf_u(acc[nt][1] + bb) << 16);
            pk[1] = f2bf_u(acc[nt][2] + bb) | (f2bf_u(acc[nt][3] + bb) << 16);
            *reinterpret_cast<u32x2*>(Vt + d * NTOK + r0) = pk;
        }
    }
}

// ------------------------------------------------------------ flash attention
// 1024 WGs = 128 q-tiles (64 rows) x 8 KV chunks (1024 keys each).
// 2 waves/WG, wave owns 32 Q rows (2 m-tiles). BN=64/iter.
// K/V fragments loaded directly from global (L2-resident); no barriers.
__global__ __launch_bounds__(128, 2) void attn(
    const us16* __restrict__ Qb, const us16* __restrict__ Kb,
    const us16* __restrict__ Vt,
    float* __restrict__ Opart, float* __restrict__ Lpart)
{
    __shared__ us16 ldsP[2][32 * 64];    // per-wave P tile, chunk swizzle

    int qtile = blockIdx.x >> 3, chunk = blockIdx.x & 7;
    int tid = threadIdx.x, w = tid >> 6, lane = tid & 63;
    int quad = lane >> 4, l15 = lane & 15;
    int qb0 = qtile * 64 + w * 32;

    bf16x8 qf[2][4];
#pragma unroll
    for (int mt = 0; mt < 2; ++mt)
#pragma unroll
        for (int ks = 0; ks < 4; ++ks)
            qf[mt][ks] = ld_frag(Qb + (qb0 + mt * 16 + l15) * 128 + ks * 32 + quad * 8);

    f32x4 o[2][8];
#pragma unroll
    for (int mt = 0; mt < 2; ++mt)
#pragma unroll
        for (int dt = 0; dt < 8; ++dt) o[mt][dt] = f32x4{0.f, 0.f, 0.f, 0.f};

    f32x4 lacc[2];
    lacc[0] = f32x4{0.f, 0.f, 0.f, 0.f};
    lacc[1] = f32x4{0.f, 0.f, 0.f, 0.f};

    u32x4 onesu;
    onesu[0] = onesu[1] = onesu[2] = onesu[3] = 0x3F803F80u;  // bf16 1.0 x8
    bf16x8 ones = __builtin_bit_cast(bf16x8, onesu);

    us16* pw = &ldsP[w][0];
    int pswz = l15 & 7;

    // loop-invariant address parts
    const us16* Kfb = Kb + (size_t)chunk * 1024 * 128 + l15 * 128 + quad * 8;
    const us16* Vfb = Vt + (size_t)l15 * NTOK + chunk * 1024 + quad * 8;

    for (int it = 0; it < 16; ++it) {
        int kof = it * 64;   // key offset within chunk

        // ---- S^T = K Q^T: lane (quad,l15) reg r = S[m=l15][n=nt*16+quad*4+r]
        f32x4 s[2][4];
#pragma unroll
        for (int mt = 0; mt < 2; ++mt)
#pragma unroll
            for (int nt = 0; nt < 4; ++nt) s[mt][nt] = f32x4{0.f, 0.f, 0.f, 0.f};

#pragma unroll
        for (int nt = 0; nt < 4; ++nt) {
            const us16* kp = Kfb + (size_t)(kof + nt * 16) * 128;
#pragma unroll
            for (int ks = 0; ks < 4; ++ks) {
                bf16x8 kf = ld_frag(kp + ks * 32);
                s[0][nt] = __builtin_amdgcn_mfma_f32_16x16x32_bf16(kf, qf[0][ks], s[0][nt], 0, 0, 0);
                s[1][nt] = __builtin_amdgcn_mfma_f32_16x16x32_bf16(kf, qf[1][ks], s[1][nt], 0, 0, 0);
            }
        }

        // ---- P = exp2(S^T) (Q pre-scaled); pack 4 n-consecutive -> b64 store
#pragma unroll
        for (int mt = 0; mt < 2; ++mt) {
#pragma unroll
            for (int nt = 0; nt < 4; ++nt) {
                float p0 = exp2f(s[mt][nt][0]);
                float p1 = exp2f(s[mt][nt][1]);
                float p2 = exp2f(s[mt][nt][2]);
                float p3 = exp2f(s[mt][nt][3]);
                u32x2 wv;
                wv[0] = pk_bf16(p0, p1);
                wv[1] = pk_bf16(p2, p3);
                int cswz = ((nt * 2 + (quad >> 1)) ^ pswz) * 8 + (quad & 1) * 4;
                *reinterpret_cast<u32x2*>(pw + (mt * 16 + l15) * 64 + cswz) = wv;
            }
        }

        // P writes are cross-lane within the wave: drain LDS before reading back
        asm volatile("s_waitcnt lgkmcnt(0)" ::: "memory");

        // ---- O += P V;  l += P @ ones
        bf16x8 afP[2][2];
#pragma unroll
        for (int mt = 0; mt < 2; ++mt)
#pragma unroll
            for (int k2 = 0; k2 < 2; ++k2)
                afP[mt][k2] = ld_frag(pw + (mt * 16 + l15) * 64 +
                                      ((k2 * 4 + quad) ^ pswz) * 8);

        lacc[0] = __builtin_amdgcn_mfma_f32_16x16x32_bf16(afP[0][0], ones, lacc[0], 0, 0, 0);
        lacc[0] = __builtin_amdgcn_mfma_f32_16x16x32_bf16(afP[0][1], ones, lacc[0], 0, 0, 0);
        lacc[1] = __builtin_amdgcn_mfma_f32_16x16x32_bf16(afP[1][0], ones, lacc[1], 0, 0, 0);
        lacc[1] = __builtin_amdgcn_mfma_f32_16x16x32_bf16(afP[1][1], ones, lacc[1], 0, 0, 0);

#pragma unroll
        for (int dt = 0; dt < 8; ++dt) {
            const us16* vp = Vfb + (size_t)dt * 16 * NTOK + kof;
#pragma unroll
            for (int k2 = 0; k2 < 2; ++k2) {
                bf16x8 bv = ld_frag(vp + k2 * 32);
                o[0][dt] = __builtin_amdgcn_mfma_f32_16x16x32_bf16(afP[0][k2], bv, o[0][dt], 0, 0, 0);
                o[1][dt] = __builtin_amdgcn_mfma_f32_16x16x32_bf16(afP[1][k2], bv, o[1][dt], 0, 0, 0);
            }
        }
        // no __syncthreads: K/V come from global; ldsP is wave-private
    }

    // ---- write unnormalized partials
#pragma unroll
    for (int mt = 0; mt < 2; ++mt)
#pragma unroll
        for (int dt = 0; dt < 8; ++dt)
#pragma unroll
            for (int r = 0; r < 4; ++r) {
                int row = qb0 + mt * 16 + quad * 4 + r;
                Opart[(size_t)(chunk * NTOK + row) * 128 + dt * 16 + l15] = o[mt][dt][r];
            }
    if (l15 == 0) {
#pragma unroll
        for (int mt = 0; mt < 2; ++mt)
#pragma unroll
            for (int r = 0; r < 4; ++r) {
                int row = qb0 + mt * 16 + quad * 4 + r;
                Lpart[chunk * NTOK + row] = lacc[mt][r];
            }
    }
}

// ------------------------------------- combine partials + output projection
// 512 blocks x 256 threads; block handles 16 rows: sum 8 chunk partials,
// normalize by sum(l), bf16 -> LDS A-tile, then GEMM @ Wo^T + bo.
// Column split: 8 nt-tiles over 4 waves -> wave w does nt = w*2+j, j<2.
__global__ __launch_bounds__(256) void combine_proj(
    const float* __restrict__ Opart, const float* __restrict__ Lpart,
    const float* __restrict__ Wo, const float* __restrict__ bo,
    float* __restrict__ out)
{
    __shared__ us16 ldsO[16 * 136];
    __shared__ float ldsL[16];

    int tile = blockIdx.x, t = threadIdx.x;
    int r0 = tile * 16;

    if (t < 16) {
        float L = 0.f;
#pragma unroll
        for (int c = 0; c < CHUNKS; ++c) L += Lpart[c * NTOK + r0 + t];
        ldsL[t] = 1.0f / L;
    }

    f32x4 acc[2];
    acc[0] = f32x4{0.f, 0.f, 0.f, 0.f};
    acc[1] = f32x4{0.f, 0.f, 0.f, 0.f};

#pragma unroll
    for (int c = 0; c < CHUNKS; ++c) {
        const float* src = Opart + (size_t)(c * NTOK + r0) * 128;
#pragma unroll
        for (int j = 0; j < 2; ++j)
            acc[j] += *reinterpret_cast<const f32x4*>(src + j * 1024 + t * 4);
    }
    __syncthreads();   // ldsL ready

#pragma unroll
    for (int j = 0; j < 2; ++j) {
        int flat = j * 1024 + t * 4;
        int row = flat >> 7, col = flat & 127;
        float sc = ldsL[row];
        u32x2 wv;
        wv[0] = pk_bf16(acc[j][0] * sc, acc[j][1] * sc);
        wv[1] = pk_bf16(acc[j][2] * sc, acc[j][3] * sc);
        *reinterpret_cast<u32x2*>(ldsO + row * 136 + col) = wv;
    }
    __syncthreads();

    // GEMM: 16 rows x 128 @ Wo^T;  wave w handles nt = w*2, w*2+1 (nt in 0..7)
    int w = t >> 6, lane = t & 63;
    int quad = lane >> 4, l15 = lane & 15;

    bf16x8 af[4];
#pragma unroll
    for (int ks = 0; ks < 4; ++ks)
        af[ks] = ld_frag(ldsO + l15 * 136 + ks * 32 + quad * 8);

    f32x4 acc2[2];
    acc2[0] = f32x4{0.f, 0.f, 0.f, 0.f};
    acc2[1] = f32x4{0.f, 0.f, 0.f, 0.f};

#pragma unroll
    for (int j = 0; j < 2; ++j) {
        int nt = w * 2 + j;
#pragma unroll
        for (int ks = 0; ks < 4; ++ks) {
            bf16x8 bfw = cvt_frag(Wo + (nt * 16 + l15) * 128 + ks * 32 + quad * 8);
            acc2[j] = __builtin_amdgcn_mfma_f32_16x16x32_bf16(af[ks], bfw, acc2[j], 0, 0, 0);
        }
    }
#pragma unroll
    for (int j = 0; j < 2; ++j) {
        int nt = w * 2 + j;
        float bb = bo[nt * 16 + l15];
#pragma unroll
        for (int r = 0; r < 4; ++r)
            out[(r0 + quad * 4 + r) * 128 + nt * 16 + l15] = acc2[j][r] + bb;
    }
}

// ------------------------------------------------------------------- launcher
extern "C" void kernel_launch(void* const* d_in, const int* in_sizes, int n_in,
                              void* d_out, int out_size, void* d_ws, size_t ws_size,
                              hipStream_t stream)
{
    const float* x  = (const float*)d_in[0];
    const float* Wq = (const float*)d_in[1];
    const float* bq = (const float*)d_in[2];
    const float* Wk = (const float*)d_in[3];
    const float* bk = (const float*)d_in[4];
    const float* Wv = (const float*)d_in[5];
    const float* bv = (const float*)d_in[6];
    const float* Wo = (const float*)d_in[7];
    const float* bo = (const float*)d_in[8];

    char* ws = (char*)d_ws;
    const size_t MB = 1024 * 1024;
    us16* Qb  = (us16*)(ws + 0 * MB);      // 2 MB
    us16* Kb  = (us16*)(ws + 2 * MB);      // 2 MB
    us16* Vt  = (us16*)(ws + 4 * MB);      // 2 MB
    float* Lp = (float*)(ws + 6 * MB);     // 256 KB
    float* Op = (float*)(ws + 8 * MB);     // 32 MB
    // total ws use: 40 MB

    proj_qkv<<<384, 256, 0, stream>>>(x, Wq, bq, Wk, bk, Wv, bv, Qb, Kb, Vt);
    attn<<<1024, 128, 0, stream>>>(Qb, Kb, Vt, Op, Lp);
    combine_proj<<<512, 256, 0, stream>>>(Op, Lp, Wo, bo, (float*)d_out);
}

// Round 7
// 152.850 us; speedup vs baseline: 1.5148x; 1.5148x over previous
//
#include <hip/hip_runtime.h>
#include <math.h>

// ----------------------------------------------------------------------------
// SingleHeadSelfAttention, N=8192, DIM=128, fp32 in/out.
// R7: revert R6 (L2-direct was latency-bound: MfmaUtil 9.8%, VALU 13.5%).
// Back to R2 staged structure (256-thr WG, 512 WGs) + software pipeline:
//   - double-buffered K/V LDS tiles (XOR-swizzled, unpadded -> 2x32KB) +
//     16KB P = 80KB = exactly 2 blocks/CU.
//   - per iter: ds_write prefetched regs -> buf[it&1]; ONE __syncthreads;
//     issue next tile's global loads (vmcnt open across compute); compute.
//   Buffer safety: iter-it writes hit the buffer last read at compute(it-2),
//   separated by the iter-(it-1) barrier.
// Swizzle: LDS slot (row, c) holds global 16B-chunk g = c ^ (row & M).
// No running max (scores bounded: exp2-arg <= ~8.4, fp32 can't overflow);
// row-sum l via ones-column MFMA; Q pre-scaled by scale*log2e;
// P round-trips per-wave LDS (C->A layout).
// ----------------------------------------------------------------------------

typedef __bf16 bf16x8 __attribute__((ext_vector_type(8)));
typedef float f32x4 __attribute__((ext_vector_type(4)));
typedef unsigned int u32x4 __attribute__((ext_vector_type(4)));
typedef unsigned int u32x2 __attribute__((ext_vector_type(2)));
typedef unsigned short us16;

#define NTOK 8192
#define CHUNKS 8

// scale * log2(e);  scale = 1/sqrt(128)
static constexpr float SCALE_L2E = 0.08838834764831845f * 1.4426950408889634f;

__device__ __forceinline__ unsigned f2bf_u(float x) {
    unsigned u = __builtin_bit_cast(unsigned, x);
    return (u + 0x7FFFu + ((u >> 16) & 1u)) >> 16;   // RNE, no NaN inputs here
}

// pack two fp32 -> bf16x2 (round-half-up; bias cancels because l uses same P)
__device__ __forceinline__ unsigned pk_bf16(float x, float y) {
    unsigned a = __builtin_bit_cast(unsigned, x) + 0x8000u;
    unsigned b = __builtin_bit_cast(unsigned, y) + 0x8000u;
#if __has_builtin(__builtin_amdgcn_perm)
    return __builtin_amdgcn_perm(b, a, 0x07060302u);  // {b.hi16 : a.hi16}
#else
    return (a >> 16) | (b & 0xFFFF0000u);
#endif
}

__device__ __forceinline__ bf16x8 ld_frag(const us16* p) {
    u32x4 u = *reinterpret_cast<const u32x4*>(p);
    return __builtin_bit_cast(bf16x8, u);
}

// load 8 consecutive fp32, convert RNE -> bf16x8 fragment
__device__ __forceinline__ bf16x8 cvt_frag(const float* p) {
    f32x4 a = *reinterpret_cast<const f32x4*>(p);
    f32x4 b = *reinterpret_cast<const f32x4*>(p + 4);
    u32x4 o;
    o[0] = f2bf_u(a[0]) | (f2bf_u(a[1]) << 16);
    o[1] = f2bf_u(a[2]) | (f2bf_u(a[3]) << 16);
    o[2] = f2bf_u(b[0]) | (f2bf_u(b[1]) << 16);
    o[3] = f2bf_u(b[2]) | (f2bf_u(b[3]) << 16);
    return __builtin_bit_cast(bf16x8, o);
}

// ------------------------------------------------------------- QKV projection
// Reads fp32 x and fp32 W directly (in-register bf16 cast).
// z=0 -> Q bf16 row-major, PRE-SCALED by scale*log2e; z=1 -> K row-major;
// z=2 -> V^T bf16 [128 x 8192]
__global__ __launch_bounds__(256) void proj_qkv(
    const float* __restrict__ x,
    const float* __restrict__ wq, const float* __restrict__ bq,
    const float* __restrict__ wk, const float* __restrict__ bk,
    const float* __restrict__ wv, const float* __restrict__ bv,
    us16* __restrict__ Qb, us16* __restrict__ Kb, us16* __restrict__ Vt)
{
    int z = blockIdx.x >> 7;
    int tile = blockIdx.x & 127;
    const float* W = z == 0 ? wq : z == 1 ? wk : wv;
    const float* bias = z == 0 ? bq : z == 1 ? bk : bv;
    float osc = z == 0 ? SCALE_L2E : 1.0f;

    int w = threadIdx.x >> 6, lane = threadIdx.x & 63;
    int quad = lane >> 4, l15 = lane & 15;
    int rbase = tile * 64 + w * 16;

    bf16x8 af[4];
#pragma unroll
    for (int ks = 0; ks < 4; ++ks)
        af[ks] = cvt_frag(x + (size_t)(rbase + l15) * 128 + ks * 32 + quad * 8);

    f32x4 acc[8];
#pragma unroll
    for (int nt = 0; nt < 8; ++nt) acc[nt] = f32x4{0.f, 0.f, 0.f, 0.f};

#pragma unroll
    for (int nt = 0; nt < 8; ++nt) {
#pragma unroll
        for (int ks = 0; ks < 4; ++ks) {
            bf16x8 bf = cvt_frag(W + (nt * 16 + l15) * 128 + ks * 32 + quad * 8);
            acc[nt] = __builtin_amdgcn_mfma_f32_16x16x32_bf16(af[ks], bf, acc[nt], 0, 0, 0);
        }
    }

#pragma unroll
    for (int nt = 0; nt < 8; ++nt) {
        float bb = bias[nt * 16 + l15];
        if (z < 2) {
            us16* Out = z == 0 ? Qb : Kb;
#pragma unroll
            for (int r = 0; r < 4; ++r)
                Out[(rbase + quad * 4 + r) * 128 + nt * 16 + l15] =
                    (us16)f2bf_u((acc[nt][r] + bb) * osc);
        } else {
            int d = nt * 16 + l15, r0 = rbase + quad * 4;
            u32x2 pk;
            pk[0] = f2bf_u(acc[nt][0] + bb) | (f2bf_u(acc[nt][1] + bb) << 16);
            pk[1] = f2bf_u(acc[nt][2] + bb) | (f2bf_u(acc[nt][3] + bb) << 16);
            *reinterpret_cast<u32x2*>(Vt + d * NTOK + r0) = pk;
        }
    }
}

// ------------------------------------------------------------ flash attention
// 512 WGs = 64 q-tiles (128 rows) x 8 KV chunks (1024 keys each).
// 4 waves/WG, wave owns 32 Q rows (2 m-tiles). BN=64/iter.
// Double-buffered LDS K/V; one barrier per iteration; prefetch in regs.
__global__ __launch_bounds__(256, 2) void attn(
    const us16* __restrict__ Qb, const us16* __restrict__ Kb,
    const us16* __restrict__ Vt,
    float* __restrict__ Opart, float* __restrict__ Lpart)
{
    __shared__ us16 ldsK[2][64 * 128];   // K tiles, 16B-chunk swizzle c^(r&15)
    __shared__ us16 ldsV[2][128 * 64];   // V^T tiles, chunk swizzle c^(r&7)
    __shared__ us16 ldsP[4][32 * 64];    // per-wave P tile, chunk swizzle

    int qtile = blockIdx.x >> 3, chunk = blockIdx.x & 7;
    int tid = threadIdx.x, w = tid >> 6, lane = tid & 63;
    int quad = lane >> 4, l15 = lane & 15;
    int qb0 = qtile * 128 + w * 32;

    const us16* Kc = Kb + (size_t)chunk * 1024 * 128;
    const us16* Vc = Vt + chunk * 1024;

    bf16x8 qf[2][4];
#pragma unroll
    for (int mt = 0; mt < 2; ++mt)
#pragma unroll
        for (int ks = 0; ks < 4; ++ks)
            qf[mt][ks] = ld_frag(Qb + (qb0 + mt * 16 + l15) * 128 + ks * 32 + quad * 8);

    f32x4 o[2][8];
#pragma unroll
    for (int mt = 0; mt < 2; ++mt)
#pragma unroll
        for (int dt = 0; dt < 8; ++dt) o[mt][dt] = f32x4{0.f, 0.f, 0.f, 0.f};

    f32x4 lacc[2];
    lacc[0] = f32x4{0.f, 0.f, 0.f, 0.f};
    lacc[1] = f32x4{0.f, 0.f, 0.f, 0.f};

    u32x4 onesu;
    onesu[0] = onesu[1] = onesu[2] = onesu[3] = 0x3F803F80u;  // bf16 1.0 x8
    bf16x8 ones = __builtin_bit_cast(bf16x8, onesu);

    us16* pw = &ldsP[w][0];
    int pswz = l15 & 7;

    // ---- prefetch tile 0 into regs
    u32x4 kreg[4], vreg[4];
#pragma unroll
    for (int c = 0; c < 4; ++c) {
        int idx = tid + c * 256;
        kreg[c] = *reinterpret_cast<const u32x4*>(
            Kc + (size_t)(idx >> 4) * 128 + (idx & 15) * 8);
        vreg[c] = *reinterpret_cast<const u32x4*>(
            Vc + (size_t)(idx >> 3) * NTOK + (idx & 7) * 8);
    }

    for (int it = 0; it < 16; ++it) {
        int cur = it & 1;
        // ---- commit prefetched tile to LDS buffer `cur` (swizzled)
#pragma unroll
        for (int c = 0; c < 4; ++c) {
            int idx = tid + c * 256;
            int kr = idx >> 4, kcc = idx & 15;
            *reinterpret_cast<u32x4*>(&ldsK[cur][kr * 128 + ((kcc ^ (kr & 15)) * 8)]) = kreg[c];
            int vr = idx >> 3, vcc = idx & 7;
            *reinterpret_cast<u32x4*>(&ldsV[cur][vr * 64 + ((vcc ^ (vr & 7)) * 8)]) = vreg[c];
        }
        __syncthreads();

        // ---- issue next tile's global loads (latency hides behind compute)
        if (it < 15) {
            int kk = (it + 1) * 64;
#pragma unroll
            for (int c = 0; c < 4; ++c) {
                int idx = tid + c * 256;
                kreg[c] = *reinterpret_cast<const u32x4*>(
                    Kc + (size_t)(kk + (idx >> 4)) * 128 + (idx & 15) * 8);
                vreg[c] = *reinterpret_cast<const u32x4*>(
                    Vc + (size_t)(idx >> 3) * NTOK + kk + (idx & 7) * 8);
            }
        }

        // ---- S^T = K Q^T: lane (quad,l15) reg r = S[m=l15][n=nt*16+quad*4+r]
        f32x4 s[2][4];
#pragma unroll
        for (int mt = 0; mt < 2; ++mt)
#pragma unroll
            for (int nt = 0; nt < 4; ++nt) s[mt][nt] = f32x4{0.f, 0.f, 0.f, 0.f};

#pragma unroll
        for (int nt = 0; nt < 4; ++nt) {
#pragma unroll
            for (int ks = 0; ks < 4; ++ks) {
                bf16x8 kf = ld_frag(&ldsK[cur][(nt * 16 + l15) * 128 +
                                               ((ks * 4 + quad) ^ l15) * 8]);
                s[0][nt] = __builtin_amdgcn_mfma_f32_16x16x32_bf16(kf, qf[0][ks], s[0][nt], 0, 0, 0);
                s[1][nt] = __builtin_amdgcn_mfma_f32_16x16x32_bf16(kf, qf[1][ks], s[1][nt], 0, 0, 0);
            }
        }

        // ---- P = exp2(S^T) (Q pre-scaled); pack 4 n-consecutive -> b64 store
#pragma unroll
        for (int mt = 0; mt < 2; ++mt) {
#pragma unroll
            for (int nt = 0; nt < 4; ++nt) {
                float p0 = exp2f(s[mt][nt][0]);
                float p1 = exp2f(s[mt][nt][1]);
                float p2 = exp2f(s[mt][nt][2]);
                float p3 = exp2f(s[mt][nt][3]);
                u32x2 wv;
                wv[0] = pk_bf16(p0, p1);
                wv[1] = pk_bf16(p2, p3);
                int cswz = ((nt * 2 + (quad >> 1)) ^ pswz) * 8 + (quad & 1) * 4;
                *reinterpret_cast<u32x2*>(pw + (mt * 16 + l15) * 64 + cswz) = wv;
            }
        }

        // P writes are cross-lane within the wave: drain LDS before reading back
        asm volatile("s_waitcnt lgkmcnt(0)" ::: "memory");

        // ---- O += P V;  l += P @ ones
        bf16x8 afP[2][2];
#pragma unroll
        for (int mt = 0; mt < 2; ++mt)
#pragma unroll
            for (int k2 = 0; k2 < 2; ++k2)
                afP[mt][k2] = ld_frag(pw + (mt * 16 + l15) * 64 +
                                      ((k2 * 4 + quad) ^ pswz) * 8);

        lacc[0] = __builtin_amdgcn_mfma_f32_16x16x32_bf16(afP[0][0], ones, lacc[0], 0, 0, 0);
        lacc[0] = __builtin_amdgcn_mfma_f32_16x16x32_bf16(afP[0][1], ones, lacc[0], 0, 0, 0);
        lacc[1] = __builtin_amdgcn_mfma_f32_16x16x32_bf16(afP[1][0], ones, lacc[1], 0, 0, 0);
        lacc[1] = __builtin_amdgcn_mfma_f32_16x16x32_bf16(afP[1][1], ones, lacc[1], 0, 0, 0);

#pragma unroll
        for (int dt = 0; dt < 8; ++dt) {
#pragma unroll
            for (int k2 = 0; k2 < 2; ++k2) {
                bf16x8 bv = ld_frag(&ldsV[cur][(dt * 16 + l15) * 64 +
                                               ((k2 * 4 + quad) ^ (l15 & 7)) * 8]);
                o[0][dt] = __builtin_amdgcn_mfma_f32_16x16x32_bf16(afP[0][k2], bv, o[0][dt], 0, 0, 0);
                o[1][dt] = __builtin_amdgcn_mfma_f32_16x16x32_bf16(afP[1][k2], bv, o[1][dt], 0, 0, 0);
            }
        }
        // next iteration's barrier separates these reads from buffer reuse
    }

    // ---- write unnormalized partials
#pragma unroll
    for (int mt = 0; mt < 2; ++mt)
#pragma unroll
        for (int dt = 0; dt < 8; ++dt)
#pragma unroll
            for (int r = 0; r < 4; ++r) {
                int row = qb0 + mt * 16 + quad * 4 + r;
                Opart[(size_t)(chunk * NTOK + row) * 128 + dt * 16 + l15] = o[mt][dt][r];
            }
    if (l15 == 0) {
#pragma unroll
        for (int mt = 0; mt < 2; ++mt)
#pragma unroll
            for (int r = 0; r < 4; ++r) {
                int row = qb0 + mt * 16 + quad * 4 + r;
                Lpart[chunk * NTOK + row] = lacc[mt][r];
            }
    }
}

// ------------------------------------- combine partials + output projection
// 512 blocks x 256 threads; block handles 16 rows: sum 8 chunk partials,
// normalize by sum(l), bf16 -> LDS A-tile, then GEMM @ Wo^T + bo.
// Column split: 8 nt-tiles over 4 waves -> wave w does nt = w*2+j, j<2.
__global__ __launch_bounds__(256) void combine_proj(
    const float* __restrict__ Opart, const float* __restrict__ Lpart,
    const float* __restrict__ Wo, const float* __restrict__ bo,
    float* __restrict__ out)
{
    __shared__ us16 ldsO[16 * 136];
    __shared__ float ldsL[16];

    int tile = blockIdx.x, t = threadIdx.x;
    int r0 = tile * 16;

    if (t < 16) {
        float L = 0.f;
#pragma unroll
        for (int c = 0; c < CHUNKS; ++c) L += Lpart[c * NTOK + r0 + t];
        ldsL[t] = 1.0f / L;
    }

    f32x4 acc[2];
    acc[0] = f32x4{0.f, 0.f, 0.f, 0.f};
    acc[1] = f32x4{0.f, 0.f, 0.f, 0.f};

#pragma unroll
    for (int c = 0; c < CHUNKS; ++c) {
        const float* src = Opart + (size_t)(c * NTOK + r0) * 128;
#pragma unroll
        for (int j = 0; j < 2; ++j)
            acc[j] += *reinterpret_cast<const f32x4*>(src + j * 1024 + t * 4);
    }
    __syncthreads();   // ldsL ready

#pragma unroll
    for (int j = 0; j < 2; ++j) {
        int flat = j * 1024 + t * 4;
        int row = flat >> 7, col = flat & 127;
        float sc = ldsL[row];
        u32x2 wv;
        wv[0] = pk_bf16(acc[j][0] * sc, acc[j][1] * sc);
        wv[1] = pk_bf16(acc[j][2] * sc, acc[j][3] * sc);
        *reinterpret_cast<u32x2*>(ldsO + row * 136 + col) = wv;
    }
    __syncthreads();

    // GEMM: 16 rows x 128 @ Wo^T;  wave w handles nt = w*2, w*2+1 (nt in 0..7)
    int w = t >> 6, lane = t & 63;
    int quad = lane >> 4, l15 = lane & 15;

    bf16x8 af[4];
#pragma unroll
    for (int ks = 0; ks < 4; ++ks)
        af[ks] = ld_frag(ldsO + l15 * 136 + ks * 32 + quad * 8);

    f32x4 acc2[2];
    acc2[0] = f32x4{0.f, 0.f, 0.f, 0.f};
    acc2[1] = f32x4{0.f, 0.f, 0.f, 0.f};

#pragma unroll
    for (int j = 0; j < 2; ++j) {
        int nt = w * 2 + j;
#pragma unroll
        for (int ks = 0; ks < 4; ++ks) {
            bf16x8 bfw = cvt_frag(Wo + (nt * 16 + l15) * 128 + ks * 32 + quad * 8);
            acc2[j] = __builtin_amdgcn_mfma_f32_16x16x32_bf16(af[ks], bfw, acc2[j], 0, 0, 0);
        }
    }
#pragma unroll
    for (int j = 0; j < 2; ++j) {
        int nt = w * 2 + j;
        float bb = bo[nt * 16 + l15];
#pragma unroll
        for (int r = 0; r < 4; ++r)
            out[(r0 + quad * 4 + r) * 128 + nt * 16 + l15] = acc2[j][r] + bb;
    }
}

// ------------------------------------------------------------------- launcher
extern "C" void kernel_launch(void* const* d_in, const int* in_sizes, int n_in,
                              void* d_out, int out_size, void* d_ws, size_t ws_size,
                              hipStream_t stream)
{
    const float* x  = (const float*)d_in[0];
    const float* Wq = (const float*)d_in[1];
    const float* bq = (const float*)d_in[2];
    const float* Wk = (const float*)d_in[3];
    const float* bk = (const float*)d_in[4];
    const float* Wv = (const float*)d_in[5];
    const float* bv = (const float*)d_in[6];
    const float* Wo = (const float*)d_in[7];
    const float* bo = (const float*)d_in[8];

    char* ws = (char*)d_ws;
    const size_t MB = 1024 * 1024;
    us16* Qb  = (us16*)(ws + 0 * MB);      // 2 MB
    us16* Kb  = (us16*)(ws + 2 * MB);      // 2 MB
    us16* Vt  = (us16*)(ws + 4 * MB);      // 2 MB
    float* Lp = (float*)(ws + 6 * MB);     // 256 KB
    float* Op = (float*)(ws + 8 * MB);     // 32 MB
    // total ws use: 40 MB

    proj_qkv<<<384, 256, 0, stream>>>(x, Wq, bq, Wk, bk, Wv, bv, Qb, Kb, Vt);
    attn<<<512, 256, 0, stream>>>(Qb, Kb, Vt, Op, Lp);
    combine_proj<<<512, 256, 0, stream>>>(Op, Lp, Wo, bo, (float*)d_out);
}